// Round 1
// baseline (746.444 us; speedup 1.0000x reference)
//
#include <hip/hip_runtime.h>

#define C_DIM 256
#define K_DIM 128
#define HW_DIM 64
#define PIX 4096      // HW*HW
#define N_IMG 32

// K0: c2[k] = sum_c cluster[k][c]^2
__global__ __launch_bounds__(128) void c2_kernel(const float* __restrict__ cl,
                                                 float* __restrict__ c2) {
    int k = threadIdx.x;  // 128 threads
    float s = 0.f;
    for (int c = 0; c < C_DIM; ++c) {
        float v = cl[k * C_DIM + c];
        s = fmaf(v, v, s);
    }
    c2[k] = s;
}

// K1: per-pixel argmin over 128 clusters.
// One thread per pixel; acc[128] in VGPRs; cluster reads are wave-uniform
// (scalar loads); x loads coalesced (consecutive lanes = consecutive w).
__global__ __launch_bounds__(256, 1) void argmin_kernel(
    const float* __restrict__ x, const float* __restrict__ cl,
    const float* __restrict__ c2, unsigned char* __restrict__ code) {
    int g = blockIdx.x * 256 + threadIdx.x;   // 0 .. 131071
    int n = g >> 12;
    int p = g & (PIX - 1);
    const float* xb = x + (size_t)n * C_DIM * PIX + p;

    float acc[K_DIM];
#pragma unroll
    for (int k = 0; k < K_DIM; ++k) acc[k] = 0.f;
    float x2 = 0.f;

    // c-chunk loop kept as a real loop (body ~1k FMAs fits I-cache);
    // inner loops fully unrolled so acc[] stays in registers.
#pragma unroll 1
    for (int c0 = 0; c0 < C_DIM; c0 += 8) {
        float xv[8];
#pragma unroll
        for (int j = 0; j < 8; ++j) xv[j] = xb[(size_t)(c0 + j) * PIX];
#pragma unroll
        for (int j = 0; j < 8; ++j) x2 = fmaf(xv[j], xv[j], x2);
#pragma unroll
        for (int k = 0; k < K_DIM; ++k) {
            const float* ck = cl + k * C_DIM + c0;  // uniform address -> s_load
#pragma unroll
            for (int j = 0; j < 8; ++j) acc[k] = fmaf(xv[j], ck[j], acc[k]);
        }
    }

    // dist assembled with the reference's op order: (x2 - 2*xc) + c2
    float best = 3.4e38f;
    int bi = 0;
#pragma unroll
    for (int k = 0; k < K_DIM; ++k) {
        float d = (x2 - 2.0f * acc[k]) + c2[k];
        if (d < best) { best = d; bi = k; }   // strict < : first-occurrence argmin
    }
    code[g] = (unsigned char)bi;
}

// K2: one wave per 8x8 histogram block; 129-bin LDS histogram, mean = count/64.
__global__ __launch_bounds__(64) void hist_kernel(const unsigned char* __restrict__ code,
                                                  float* __restrict__ out) {
    __shared__ int hist[K_DIM + 1];
    int b = blockIdx.x;          // n*64 + sy*8 + sx
    int t = threadIdx.x;         // 0..63
    int n = b >> 6;
    int sy = (b >> 3) & 7;
    int sx = b & 7;

    hist[t] = 0;
    hist[t + 64] = 0;
    if (t == 0) hist[128] = 0;
    __syncthreads();

    int h = sy * 8 + (t >> 3);
    int w = sx * 8 + (t & 7);
    int c = code[n * PIX + h * HW_DIM + w];
    atomicAdd(&hist[c + 1], 1);
    __syncthreads();

    const float inv = 1.0f / 64.0f;
    out[(size_t)b * (K_DIM + 1) + t] = hist[t] * inv;
    out[(size_t)b * (K_DIM + 1) + 64 + t] = hist[64 + t] * inv;
    if (t == 0) out[(size_t)b * (K_DIM + 1) + 128] = hist[128] * inv;
}

extern "C" void kernel_launch(void* const* d_in, const int* in_sizes, int n_in,
                              void* d_out, int out_size, void* d_ws, size_t ws_size,
                              hipStream_t stream) {
    const float* x  = (const float*)d_in[0];       // (32, 256, 64, 64) fp32
    const float* cl = (const float*)d_in[1];       // (128, 256) fp32
    float* out = (float*)d_out;                    // (32, 64, 129) fp32

    float* c2 = (float*)d_ws;                      // 128 floats
    unsigned char* code = (unsigned char*)d_ws + 512;  // 131072 bytes

    c2_kernel<<<1, 128, 0, stream>>>(cl, c2);
    argmin_kernel<<<(N_IMG * PIX) / 256, 256, 0, stream>>>(x, cl, c2, code);
    hist_kernel<<<N_IMG * 64, 64, 0, stream>>>(code, out);
}

// Round 2
// 303.192 us; speedup vs baseline: 2.4619x; 2.4619x over previous
//
#include <hip/hip_runtime.h>

#define C_DIM 256
#define K_DIM 128
#define HW_DIM 64
#define PIX 4096      // HW*HW
#define N_IMG 32

// P0: transpose clusters to clT[c][k]  (so a wave's 32-cluster slice at one c
// is 32 contiguous floats -> wide scalar loads in the main kernel)
__global__ __launch_bounds__(256) void prep_kernel(const float* __restrict__ cl,
                                                   float* __restrict__ clT) {
    int t = blockIdx.x * 256 + threadIdx.x;   // 0 .. 32767
    int k = t >> 8;
    int c = t & 255;
    clT[c * K_DIM + k] = cl[t];               // read coalesced, write scattered (tiny)
}

// P1: c2[k] = sum_c cl[k][c]^2 — float4 row reads, 64 independent loads/thread
__global__ __launch_bounds__(128) void c2_kernel(const float* __restrict__ cl,
                                                 float* __restrict__ c2) {
    int k = threadIdx.x;  // 128 threads, 1 block
    const float4* row = (const float4*)(cl + k * C_DIM);
    float s = 0.f;
#pragma unroll
    for (int i = 0; i < C_DIM / 4; ++i) {
        float4 v = row[i];
        s = fmaf(v.x, v.x, s);
        s = fmaf(v.y, v.y, s);
        s = fmaf(v.z, v.z, s);
        s = fmaf(v.w, v.w, s);
    }
    c2[k] = s;
}

// K1: 256-thread block = 4 waves; all waves share the same 64 pixels,
// each wave handles 32 of the 128 clusters (k-split => acc[32] fits in VGPRs,
// cluster addresses stay wave-uniform => scalar loads).
__global__ __launch_bounds__(256) void argmin_kernel(
    const float* __restrict__ x, const float* __restrict__ clT,
    const float* __restrict__ c2v, unsigned char* __restrict__ code) {
    __shared__ unsigned long long red[4][64];

    int lane = threadIdx.x & 63;
    int wid  = __builtin_amdgcn_readfirstlane(threadIdx.x >> 6);
    int k0   = wid * 32;

    int g = blockIdx.x * 64 + lane;           // pixel id, 0 .. 131071
    const float* xb = x + (size_t)(g >> 12) * (C_DIM * PIX) + (g & (PIX - 1));

    float acc[32];
#pragma unroll
    for (int k = 0; k < 32; ++k) acc[k] = 0.f;
    float x2 = 0.f;

#pragma unroll 1
    for (int c0 = 0; c0 < C_DIM; c0 += 8) {
        float xv[8];
#pragma unroll
        for (int j = 0; j < 8; ++j) xv[j] = xb[(size_t)(c0 + j) * PIX];  // coalesced
#pragma unroll
        for (int j = 0; j < 8; ++j) x2 = fmaf(xv[j], xv[j], x2);
#pragma unroll
        for (int j = 0; j < 8; ++j) {
            const float* ct = clT + (c0 + j) * K_DIM + k0;  // wave-uniform -> s_load
#pragma unroll
            for (int k = 0; k < 32; ++k) acc[k] = fmaf(xv[j], ct[k], acc[k]);
        }
    }

    // local argmin over this wave's 32 clusters; key = (ordered dist bits)<<32 | k
    // so min() gives smallest dist, ties -> smallest k (reference first-occurrence)
    unsigned long long bestkey = ~0ull;
#pragma unroll
    for (int k = 0; k < 32; ++k) {
        float d = (x2 - 2.0f * acc[k]) + c2v[k0 + k];   // reference op order
        unsigned int db = __float_as_uint(d);
        db ^= (db & 0x80000000u) ? 0xFFFFFFFFu : 0x80000000u;  // monotonic map
        unsigned long long key = ((unsigned long long)db << 32) | (unsigned)(k0 + k);
        bestkey = key < bestkey ? key : bestkey;
    }

    red[wid][lane] = bestkey;
    __syncthreads();
    if (wid == 0) {
        unsigned long long m0 = red[0][lane], m1 = red[1][lane];
        unsigned long long m2 = red[2][lane], m3 = red[3][lane];
        unsigned long long m = min(min(m0, m1), min(m2, m3));
        code[g] = (unsigned char)(m & 0xFFu);
    }
}

// K2: 4 histogram tiles per 256-thread block (one per wave); 129-bin LDS hist.
__global__ __launch_bounds__(256) void hist_kernel(const unsigned char* __restrict__ code,
                                                   float* __restrict__ out) {
    __shared__ int hist[4][K_DIM + 1];
    int wid = threadIdx.x >> 6, lane = threadIdx.x & 63;
    int b = blockIdx.x * 4 + wid;             // tile id 0 .. 2047
    int n = b >> 6, sy = (b >> 3) & 7, sx = b & 7;

    hist[wid][lane] = 0;
    hist[wid][lane + 64] = 0;
    if (lane == 0) hist[wid][128] = 0;
    __syncthreads();

    int h = sy * 8 + (lane >> 3);
    int w = sx * 8 + (lane & 7);
    int c = code[n * PIX + h * HW_DIM + w];
    atomicAdd(&hist[wid][c + 1], 1);
    __syncthreads();

    const float inv = 1.0f / 64.0f;
    out[(size_t)b * (K_DIM + 1) + lane] = hist[wid][lane] * inv;
    out[(size_t)b * (K_DIM + 1) + 64 + lane] = hist[wid][lane + 64] * inv;
    if (lane == 0) out[(size_t)b * (K_DIM + 1) + 128] = hist[wid][128] * inv;
}

extern "C" void kernel_launch(void* const* d_in, const int* in_sizes, int n_in,
                              void* d_out, int out_size, void* d_ws, size_t ws_size,
                              hipStream_t stream) {
    const float* x  = (const float*)d_in[0];       // (32, 256, 64, 64) fp32
    const float* cl = (const float*)d_in[1];       // (128, 256) fp32
    float* out = (float*)d_out;                    // (32, 64, 129) fp32

    float* clT = (float*)d_ws;                                  // 128 KiB
    float* c2  = (float*)((char*)d_ws + K_DIM * C_DIM * 4);     // 512 B
    unsigned char* code = (unsigned char*)d_ws + K_DIM * C_DIM * 4 + 512;  // 128 KiB

    prep_kernel<<<K_DIM * C_DIM / 256, 256, 0, stream>>>(cl, clT);
    c2_kernel<<<1, 128, 0, stream>>>(cl, c2);
    argmin_kernel<<<(N_IMG * PIX) / 64, 256, 0, stream>>>(x, clT, c2, code);
    hist_kernel<<<(N_IMG * 64) / 4, 256, 0, stream>>>(code, out);
}

// Round 3
// 279.124 us; speedup vs baseline: 2.6742x; 1.0862x over previous
//
#include <hip/hip_runtime.h>

#define C_DIM 256
#define K_DIM 128
#define HW_DIM 64
#define PIX 4096      // HW*HW
#define N_IMG 32
#define CHUNK 8
#define NCHUNK (C_DIM / CHUNK)

// P: fused transpose + c2. One block per cluster row.
// c2 accumulation order identical to round-2's proven-exact kernel
// (serial fmaf over ascending c, x/y/z/w within each float4).
__global__ __launch_bounds__(64) void prep_kernel(const float* __restrict__ cl,
                                                  float* __restrict__ clT,
                                                  float* __restrict__ c2) {
    int k = blockIdx.x;
    int lane = threadIdx.x;
    const float4* row = (const float4*)(cl + k * C_DIM);
    float4 v = row[lane];
    clT[(lane * 4 + 0) * K_DIM + k] = v.x;
    clT[(lane * 4 + 1) * K_DIM + k] = v.y;
    clT[(lane * 4 + 2) * K_DIM + k] = v.z;
    clT[(lane * 4 + 3) * K_DIM + k] = v.w;
    if (lane == 0) {
        float s = 0.f;
#pragma unroll
        for (int i = 0; i < C_DIM / 4; ++i) {
            float4 u = row[i];
            s = fmaf(u.x, u.x, s);
            s = fmaf(u.y, u.y, s);
            s = fmaf(u.z, u.z, s);
            s = fmaf(u.w, u.w, s);
        }
        c2[k] = s;
    }
}

// Main: block = 256 threads (4 waves) handles an 8-row x 16-col pixel region
// (= 2 adjacent 8x8 histogram tiles). All waves share the 128 pixels; each
// wave owns 32 of the 128 clusters. Cluster chunks staged in double-buffered
// LDS, read back via same-address ds_read_b128 broadcasts. 2 px per thread.
// Epilogue: cross-wave argmin merge + fused LDS histogram + output write.
__global__ __launch_bounds__(256) void main_kernel(
    const float* __restrict__ x, const float* __restrict__ clT,
    const float* __restrict__ c2v, float* __restrict__ out) {
    __shared__ float cbuf[2][CHUNK * K_DIM];          // 2 x 4 KiB
    __shared__ unsigned long long red[4][2][64];      // 4 KiB
    __shared__ int hist[2][K_DIM + 1];

    int t = threadIdx.x;
    int lane = t & 63;
    int wid = __builtin_amdgcn_readfirstlane(t >> 6);
    int k0 = wid * 32;

    int b = blockIdx.x;
    int n = b >> 5, sy = (b >> 2) & 7, sxx = b & 3;

    if (t < K_DIM + 1) { hist[0][t] = 0; hist[1][t] = 0; }

    // pixel addressing: px0 = (h = sy*8 + lane>>4, w = sxx*16 + lane&15),
    // px1 = px0 + 4 rows
    const float* xb = x + (size_t)n * (C_DIM * PIX)
                    + (sy * 8 + (lane >> 4)) * HW_DIM + sxx * 16 + (lane & 15);

    const float4* cg = (const float4*)clT;   // chunk ci = cg[ci*256 + t], contiguous

    float4 cst = cg[t];                      // prefetch chunk 0
    float xa[CHUNK], xbv[CHUNK], xaN[CHUNK], xbN[CHUNK];
#pragma unroll
    for (int j = 0; j < CHUNK; ++j) {
        xa[j]  = xb[(size_t)j * PIX];
        xbv[j] = xb[(size_t)j * PIX + 4 * HW_DIM];
    }

    float acc0[32], acc1[32];
#pragma unroll
    for (int k = 0; k < 32; ++k) { acc0[k] = 0.f; acc1[k] = 0.f; }
    float x20 = 0.f, x21 = 0.f;

#pragma unroll 1
    for (int ci = 0; ci < NCHUNK; ++ci) {
        int par = ci & 1;
        ((float4*)cbuf[par])[t] = cst;
        __syncthreads();                      // cbuf[par] ready

        if (ci + 1 < NCHUNK) {                // prefetch next chunk
            cst = cg[(ci + 1) * 256 + t];
            const float* xn = xb + (size_t)(ci + 1) * CHUNK * PIX;
#pragma unroll
            for (int j = 0; j < CHUNK; ++j) {
                xaN[j] = xn[(size_t)j * PIX];
                xbN[j] = xn[(size_t)j * PIX + 4 * HW_DIM];
            }
        }

#pragma unroll
        for (int j = 0; j < CHUNK; ++j) {
            x20 = fmaf(xa[j],  xa[j],  x20);
            x21 = fmaf(xbv[j], xbv[j], x21);
            const float4* cb = (const float4*)&cbuf[par][j * K_DIM + k0];
#pragma unroll
            for (int q = 0; q < 8; ++q) {
                float4 cv = cb[q];            // broadcast ds_read_b128
                acc0[q * 4 + 0] = fmaf(xa[j],  cv.x, acc0[q * 4 + 0]);
                acc0[q * 4 + 1] = fmaf(xa[j],  cv.y, acc0[q * 4 + 1]);
                acc0[q * 4 + 2] = fmaf(xa[j],  cv.z, acc0[q * 4 + 2]);
                acc0[q * 4 + 3] = fmaf(xa[j],  cv.w, acc0[q * 4 + 3]);
                acc1[q * 4 + 0] = fmaf(xbv[j], cv.x, acc1[q * 4 + 0]);
                acc1[q * 4 + 1] = fmaf(xbv[j], cv.y, acc1[q * 4 + 1]);
                acc1[q * 4 + 2] = fmaf(xbv[j], cv.z, acc1[q * 4 + 2]);
                acc1[q * 4 + 3] = fmaf(xbv[j], cv.w, acc1[q * 4 + 3]);
            }
        }
        __syncthreads();                      // all reads of cbuf[par] done
#pragma unroll
        for (int j = 0; j < CHUNK; ++j) { xa[j] = xaN[j]; xbv[j] = xbN[j]; }
    }

    // per-wave argmin over its 32 clusters, both pixels.
    // dist assembled exactly as reference: (x2 - 2*xc) + c2
    unsigned long long best0 = ~0ull, best1 = ~0ull;
#pragma unroll
    for (int k = 0; k < 32; ++k) {
        float c2k = c2v[k0 + k];
        float d0 = (x20 - 2.0f * acc0[k]) + c2k;
        float d1 = (x21 - 2.0f * acc1[k]) + c2k;
        unsigned int u0 = __float_as_uint(d0);
        unsigned int u1 = __float_as_uint(d1);
        u0 ^= (u0 & 0x80000000u) ? 0xFFFFFFFFu : 0x80000000u;
        u1 ^= (u1 & 0x80000000u) ? 0xFFFFFFFFu : 0x80000000u;
        unsigned long long key0 = ((unsigned long long)u0 << 32) | (unsigned)(k0 + k);
        unsigned long long key1 = ((unsigned long long)u1 << 32) | (unsigned)(k0 + k);
        best0 = key0 < best0 ? key0 : best0;
        best1 = key1 < best1 ? key1 : best1;
    }
    red[wid][0][lane] = best0;
    red[wid][1][lane] = best1;
    __syncthreads();

    if (wid == 0) {
        unsigned long long m0 = min(min(red[0][0][lane], red[1][0][lane]),
                                    min(red[2][0][lane], red[3][0][lane]));
        unsigned long long m1 = min(min(red[0][1][lane], red[1][1][lane]),
                                    min(red[2][1][lane], red[3][1][lane]));
        int tile = (lane & 15) >> 3;
        atomicAdd(&hist[tile][(int)(m0 & 0xFFu) + 1], 1);
        atomicAdd(&hist[tile][(int)(m1 & 0xFFu) + 1], 1);
    }
    __syncthreads();

    const float inv = 1.0f / 64.0f;
    int obase = ((n * 64) + sy * 8 + sxx * 2) * (K_DIM + 1);
    for (int idx = t; idx < 2 * (K_DIM + 1); idx += 256) {
        int tile = idx >= (K_DIM + 1);
        int bin = idx - tile * (K_DIM + 1);
        out[obase + tile * (K_DIM + 1) + bin] = hist[tile][bin] * inv;
    }
}

extern "C" void kernel_launch(void* const* d_in, const int* in_sizes, int n_in,
                              void* d_out, int out_size, void* d_ws, size_t ws_size,
                              hipStream_t stream) {
    const float* x  = (const float*)d_in[0];       // (32, 256, 64, 64) fp32
    const float* cl = (const float*)d_in[1];       // (128, 256) fp32
    float* out = (float*)d_out;                    // (32, 64, 129) fp32

    float* clT = (float*)d_ws;                              // 128 KiB
    float* c2  = (float*)((char*)d_ws + K_DIM * C_DIM * 4); // 512 B

    prep_kernel<<<K_DIM, 64, 0, stream>>>(cl, clT, c2);
    main_kernel<<<(N_IMG * PIX) / 128, 256, 0, stream>>>(x, clT, c2, out);
}

// Round 5
// 228.546 us; speedup vs baseline: 3.2660x; 1.2213x over previous
//
#include <hip/hip_runtime.h>

#define C_DIM 256
#define K_DIM 128
#define HW_DIM 64
#define PIX 4096
#define N_IMG 32
#define ROWU 36            // ushorts per LDS A-row: 32 data + 4 pad (72 B, 8B-aligned)

using short8 = __attribute__((ext_vector_type(8))) short;
using f32x4  = __attribute__((ext_vector_type(4))) float;

union frag_u { unsigned long long u[2]; short8 s; };

__device__ __forceinline__ unsigned rne_bf16(float v) {
    unsigned u = __float_as_uint(v);
    return (u + 0x7fffu + ((u >> 16) & 1u)) >> 16;
}
__device__ __forceinline__ float bf_up(unsigned h) { return __uint_as_float(h << 16); }

// split x = hi + mid + lo (each exactly representable; residual ~2^-26*x)
__device__ __forceinline__ void split3(float v, unsigned& h, unsigned& m, unsigned& l) {
    h = rne_bf16(v);
    float r1 = v - bf_up(h);       // exact (Sterbenz)
    m = rne_bf16(r1);
    float r2 = r1 - bf_up(m);      // exact
    l = rne_bf16(r2);
}

__device__ __forceinline__ unsigned long long umin64(unsigned long long a, unsigned long long b) {
    return a < b ? a : b;
}
__device__ __forceinline__ unsigned mono(float d) {
    unsigned u = __float_as_uint(d);
    return u ^ ((u & 0x80000000u) ? 0xFFFFFFFFu : 0x80000000u);
}

// P: per cluster k: 3-way bf16 split -> Bt[k][768] (planes hi/mid/lo), plus exact c2
__global__ __launch_bounds__(64) void prep_kernel(const float* __restrict__ cl,
                                                  unsigned short* __restrict__ Bt,
                                                  float* __restrict__ c2) {
    int k = blockIdx.x;
    int lane = threadIdx.x;
    const float4* row = (const float4*)(cl + k * C_DIM);
    float4 v = row[lane];
    float vv[4] = {v.x, v.y, v.z, v.w};
    unsigned short* bk = Bt + k * 768 + lane * 4;
#pragma unroll
    for (int i = 0; i < 4; ++i) {
        unsigned h, m, l;
        split3(vv[i], h, m, l);
        bk[i]       = (unsigned short)h;
        bk[256 + i] = (unsigned short)m;
        bk[512 + i] = (unsigned short)l;
    }
    if (lane == 0) {   // identical op order to round-3's proven-exact c2
        float s = 0.f;
#pragma unroll
        for (int i = 0; i < C_DIM / 4; ++i) {
            float4 u = row[i];
            s = fmaf(u.x, u.x, s);
            s = fmaf(u.y, u.y, s);
            s = fmaf(u.z, u.z, s);
            s = fmaf(u.w, u.w, s);
        }
        c2[k] = s;
    }
}

// Main: block = 256 thr (4 waves) computes S[128 px][128 k] via 16x16x32 bf16
// MFMA, 3-way split with cross terms: pairs (A-plane, B-plane) =
// (h,h) (h,m) (m,h) (h,l) (m,m) (l,h)  -> product error ~2^-27/channel,
// below the fp32-reorder noise rounds 1-3 proved flip-free.
// Wave w owns n in [32w, 32w+32); all waves share the 128 px (M).
__global__ __launch_bounds__(256) void main_kernel(
    const float* __restrict__ x, const unsigned short* __restrict__ Bt,
    const float* __restrict__ c2v, unsigned char* __restrict__ code) {

    __shared__ unsigned short Ap[2][3][128 * ROWU];   // 55296 B
    __shared__ float x2p[2][128];                     // 1024 B
    __shared__ unsigned long long red[4][128];        // 4096 B

    const int t    = threadIdx.x;
    const int lane = t & 63;
    const int w    = t >> 6;
    const int q    = lane >> 4;
    const int l15  = lane & 15;

    const int px = t & 127;        // conversion: this thread's pixel row
    const int h  = t >> 7;         // conversion: c-half (0: c 0-15, 1: c 16-31 of chunk)

    const int b   = blockIdx.x;
    const int img = b >> 5;
    const int pb  = (b & 31) * 128;

    const float* xg = x + (size_t)img * (C_DIM * PIX) + pb + px;

    f32x4 acc[8][2];
#pragma unroll
    for (int m = 0; m < 8; ++m)
#pragma unroll
        for (int ns = 0; ns < 2; ++ns) acc[m][ns] = (f32x4){0.f, 0.f, 0.f, 0.f};

    float xr[16];
#pragma unroll
    for (int j = 0; j < 16; ++j) xr[j] = xg[(size_t)(h * 16 + j) * PIX];

    float x2part = 0.f;
    const unsigned short* bt0 = Bt + (w * 32 + l15) * 768 + q * 8;
    const unsigned short* bt1 = bt0 + 16 * 768;

#pragma unroll 2
    for (int ci = 0; ci < 8; ++ci) {
        const int par = ci & 1;

        // ---- convert xr -> 3 bf16 planes in LDS[par], accumulate x2 ----
#pragma unroll
        for (int g = 0; g < 2; ++g) {
            unsigned pk0[4], pk1[4], pk2[4];
#pragma unroll
            for (int jj = 0; jj < 4; ++jj) {
                float v0 = xr[g * 8 + jj * 2], v1 = xr[g * 8 + jj * 2 + 1];
                unsigned h0, m0, l0, h1, m1, l1;
                split3(v0, h0, m0, l0);
                split3(v1, h1, m1, l1);
                pk0[jj] = h0 | (h1 << 16);
                pk1[jj] = m0 | (m1 << 16);
                pk2[jj] = l0 | (l1 << 16);
                x2part = fmaf(v0, v0, x2part);
                x2part = fmaf(v1, v1, x2part);
            }
            int base = px * ROWU + h * 16 + g * 8;    // ushort index, byte 8-aligned
            *(uint2*)&Ap[par][0][base]     = make_uint2(pk0[0], pk0[1]);
            *(uint2*)&Ap[par][0][base + 4] = make_uint2(pk0[2], pk0[3]);
            *(uint2*)&Ap[par][1][base]     = make_uint2(pk1[0], pk1[1]);
            *(uint2*)&Ap[par][1][base + 4] = make_uint2(pk1[2], pk1[3]);
            *(uint2*)&Ap[par][2][base]     = make_uint2(pk2[0], pk2[1]);
            *(uint2*)&Ap[par][2][base + 4] = make_uint2(pk2[2], pk2[3]);
        }
        if (ci == 7) x2p[h][px] = x2part;

        // ---- prefetch next x chunk (HBM latency hidden behind MFMA phase) ----
        float xr2[16];
        if (ci < 7) {
#pragma unroll
            for (int j = 0; j < 16; ++j)
                xr2[j] = xg[(size_t)((ci + 1) * 32 + h * 16 + j) * PIX];
        }

        __syncthreads();   // LDS[par] ready

        // ---- MFMA phase: pairs grouped by A-plane so each A-frag loads once.
        // pa=0(h): pb {h,m,l}; pa=1(m): pb {h,m}; pa=2(l): pb {h}.
#pragma unroll
        for (int pa = 0; pa < 3; ++pa) {
            const int npb = (pa == 0) ? 3 : ((pa == 1) ? 2 : 1);
            frag_u bf[3][2];
#pragma unroll
            for (int pbp = 0; pbp < 3; ++pbp) {
                if (pbp < npb) {
                    const int ko = pbp * 256 + ci * 32;
                    bf[pbp][0].s = *(const short8*)(bt0 + ko);   // L2-hot
                    bf[pbp][1].s = *(const short8*)(bt1 + ko);
                }
            }
#pragma unroll
            for (int m = 0; m < 8; ++m) {
                const unsigned short* ap = &Ap[par][pa][(m * 16 + l15) * ROWU + q * 8];
                frag_u af;
                af.u[0] = *(const unsigned long long*)ap;
                af.u[1] = *(const unsigned long long*)(ap + 4);
#pragma unroll
                for (int pbp = 0; pbp < 3; ++pbp) {
                    if (pbp < npb) {
                        acc[m][0] = __builtin_amdgcn_mfma_f32_16x16x32_bf16(af.s, bf[pbp][0].s, acc[m][0], 0, 0, 0);
                        acc[m][1] = __builtin_amdgcn_mfma_f32_16x16x32_bf16(af.s, bf[pbp][1].s, acc[m][1], 0, 0, 0);
                    }
                }
            }
        }
        if (ci < 7) {
#pragma unroll
            for (int j = 0; j < 16; ++j) xr[j] = xr2[j];
        }
    }

    __syncthreads();   // x2p complete

    // ---- epilogue: dist = (x2 - 2*S) + c2, argmin over n ----
    const float c2a0 = c2v[w * 32 + l15];
    const float c2a1 = c2v[w * 32 + 16 + l15];
    const unsigned n0 = (unsigned)(w * 32 + l15);
    const unsigned n1 = n0 + 16;

#pragma unroll
    for (int m = 0; m < 8; ++m) {
#pragma unroll
        for (int r = 0; r < 4; ++r) {
            int pxl = m * 16 + q * 4 + r;             // C/D: row = quad*4 + reg
            float x2v = x2p[0][pxl] + x2p[1][pxl];
            float d0 = (x2v - 2.0f * acc[m][0][r]) + c2a0;
            float d1 = (x2v - 2.0f * acc[m][1][r]) + c2a1;
            unsigned long long k0 = ((unsigned long long)mono(d0) << 32) | n0;
            unsigned long long k1 = ((unsigned long long)mono(d1) << 32) | n1;
            unsigned long long best = umin64(k0, k1);
            best = umin64(best, __shfl_xor(best, 1));
            best = umin64(best, __shfl_xor(best, 2));
            best = umin64(best, __shfl_xor(best, 4));
            best = umin64(best, __shfl_xor(best, 8));
            if (l15 == 0) red[w][pxl] = best;
        }
    }
    __syncthreads();

    if (t < 128) {
        unsigned long long m0 = umin64(umin64(red[0][t], red[1][t]),
                                       umin64(red[2][t], red[3][t]));
        code[(size_t)img * PIX + pb + t] = (unsigned char)(m0 & 0xFFu);
    }
}

// K2: 4 histogram tiles per 256-thread block (round-2 proven-exact kernel)
__global__ __launch_bounds__(256) void hist_kernel(const unsigned char* __restrict__ code,
                                                   float* __restrict__ out) {
    __shared__ int hist[4][K_DIM + 1];
    int wid = threadIdx.x >> 6, lane = threadIdx.x & 63;
    int b = blockIdx.x * 4 + wid;
    int n = b >> 6, sy = (b >> 3) & 7, sx = b & 7;

    hist[wid][lane] = 0;
    hist[wid][lane + 64] = 0;
    if (lane == 0) hist[wid][128] = 0;
    __syncthreads();

    int hh = sy * 8 + (lane >> 3);
    int ww = sx * 8 + (lane & 7);
    int c = code[n * PIX + hh * HW_DIM + ww];
    atomicAdd(&hist[wid][c + 1], 1);
    __syncthreads();

    const float inv = 1.0f / 64.0f;
    out[(size_t)b * (K_DIM + 1) + lane] = hist[wid][lane] * inv;
    out[(size_t)b * (K_DIM + 1) + 64 + lane] = hist[wid][lane + 64] * inv;
    if (lane == 0) out[(size_t)b * (K_DIM + 1) + 128] = hist[wid][128] * inv;
}

extern "C" void kernel_launch(void* const* d_in, const int* in_sizes, int n_in,
                              void* d_out, int out_size, void* d_ws, size_t ws_size,
                              hipStream_t stream) {
    const float* x  = (const float*)d_in[0];       // (32, 256, 64, 64) fp32
    const float* cl = (const float*)d_in[1];       // (128, 256) fp32
    float* out = (float*)d_out;                    // (32, 64, 129) fp32

    unsigned short* Bt = (unsigned short*)d_ws;                  // 196608 B
    float* c2 = (float*)((char*)d_ws + 196608);                  // 512 B
    unsigned char* code = (unsigned char*)d_ws + 197120;         // 131072 B

    prep_kernel<<<K_DIM, 64, 0, stream>>>(cl, Bt, c2);
    main_kernel<<<(N_IMG * PIX) / 128, 256, 0, stream>>>(x, Bt, c2, code);
    hist_kernel<<<(N_IMG * 64) / 4, 256, 0, stream>>>(code, out);
}

// Round 6
// 228.169 us; speedup vs baseline: 3.2714x; 1.0017x over previous
//
#include <hip/hip_runtime.h>

#define C_DIM 256
#define K_DIM 128
#define HW_DIM 64
#define PIX 4096
#define N_IMG 32
#define ROWU 40            // ushorts per LDS A-row: 32 data + 8 pad (80 B, 16B-aligned)

using short8 = __attribute__((ext_vector_type(8))) short;
using f32x4  = __attribute__((ext_vector_type(4))) float;

__device__ __forceinline__ unsigned rne_bf16(float v) {
    unsigned u = __float_as_uint(v);
    return (u + 0x7fffu + ((u >> 16) & 1u)) >> 16;
}
__device__ __forceinline__ float bf_up(unsigned h) { return __uint_as_float(h << 16); }

// split x = hi + mid + lo (each exactly representable; residual ~2^-26*x)
__device__ __forceinline__ void split3(float v, unsigned& h, unsigned& m, unsigned& l) {
    h = rne_bf16(v);
    float r1 = v - bf_up(h);       // exact (Sterbenz)
    m = rne_bf16(r1);
    float r2 = r1 - bf_up(m);      // exact
    l = rne_bf16(r2);
}

__device__ __forceinline__ unsigned long long umin64(unsigned long long a, unsigned long long b) {
    return a < b ? a : b;
}
__device__ __forceinline__ unsigned mono(float d) {
    unsigned u = __float_as_uint(d);
    return u ^ ((u & 0x80000000u) ? 0xFFFFFFFFu : 0x80000000u);
}

// P: per cluster k: 3-way bf16 split -> Bt[k][768] (planes hi/mid/lo), plus exact c2
__global__ __launch_bounds__(64) void prep_kernel(const float* __restrict__ cl,
                                                  unsigned short* __restrict__ Bt,
                                                  float* __restrict__ c2) {
    int k = blockIdx.x;
    int lane = threadIdx.x;
    const float4* row = (const float4*)(cl + k * C_DIM);
    float4 v = row[lane];
    float vv[4] = {v.x, v.y, v.z, v.w};
    unsigned short* bk = Bt + k * 768 + lane * 4;
#pragma unroll
    for (int i = 0; i < 4; ++i) {
        unsigned h, m, l;
        split3(vv[i], h, m, l);
        bk[i]       = (unsigned short)h;
        bk[256 + i] = (unsigned short)m;
        bk[512 + i] = (unsigned short)l;
    }
    if (lane == 0) {   // identical op order to proven-exact c2
        float s = 0.f;
#pragma unroll
        for (int i = 0; i < C_DIM / 4; ++i) {
            float4 u = row[i];
            s = fmaf(u.x, u.x, s);
            s = fmaf(u.y, u.y, s);
            s = fmaf(u.z, u.z, s);
            s = fmaf(u.w, u.w, s);
        }
        c2[k] = s;
    }
}

// Main: block = 256 thr (4 waves) computes S[128 px][128 k] via 16x16x32 bf16
// MFMA, 3-way split with cross terms (h,h)(h,m)(m,h)(h,l)(m,m)(l,h).
// Single-buffered A-tile in LDS (2 barriers/chunk) -> 35.8 KB -> 4 blocks/CU.
// B-fragments: 6 unique per chunk, loaded before the convert phase (L2 latency
// hidden behind convert VALU + barrier). Wave w owns n in [32w, 32w+32).
__global__ __launch_bounds__(256) void main_kernel(
    const float* __restrict__ x, const unsigned short* __restrict__ Bt,
    const float* __restrict__ c2v, unsigned char* __restrict__ code) {

    __shared__ __align__(16) unsigned short Ap[3][128 * ROWU];  // 30720 B
    __shared__ float x2p[2][128];                               // 1024 B
    __shared__ unsigned long long red[4][128];                  // 4096 B

    const int t    = threadIdx.x;
    const int lane = t & 63;
    const int w    = t >> 6;
    const int q    = lane >> 4;
    const int l15  = lane & 15;

    const int px = t & 127;        // conversion: this thread's pixel row
    const int h  = t >> 7;         // conversion: c-half (0: c 0-15, 1: c 16-31)

    const int b   = blockIdx.x;
    const int img = b >> 5;
    const int pb  = (b & 31) * 128;

    const float* xg = x + (size_t)img * (C_DIM * PIX) + pb + px;

    f32x4 acc[8][2];
#pragma unroll
    for (int m = 0; m < 8; ++m)
#pragma unroll
        for (int ns = 0; ns < 2; ++ns) acc[m][ns] = (f32x4){0.f, 0.f, 0.f, 0.f};

    float xr[16];
#pragma unroll
    for (int j = 0; j < 16; ++j) xr[j] = xg[(size_t)(h * 16 + j) * PIX];

    float x2part = 0.f;
    const unsigned short* btb = Bt + (w * 32 + l15) * 768 + q * 8;

    short8 bv[3][2];

#pragma unroll 1
    for (int ci = 0; ci < 8; ++ci) {
        // ---- B-fragments for this chunk: 6 unique (plane x n-half), L2-hot.
        // Issued first so latency hides behind the convert phase + barrier.
#pragma unroll
        for (int p = 0; p < 3; ++p) {
            bv[p][0] = *(const short8*)(btb + p * 256 + ci * 32);
            bv[p][1] = *(const short8*)(btb + 16 * 768 + p * 256 + ci * 32);
        }

        // ---- convert xr -> 3 bf16 planes in LDS, accumulate x2 ----
#pragma unroll
        for (int g = 0; g < 2; ++g) {
            unsigned pk0[4], pk1[4], pk2[4];
#pragma unroll
            for (int jj = 0; jj < 4; ++jj) {
                float v0 = xr[g * 8 + jj * 2], v1 = xr[g * 8 + jj * 2 + 1];
                unsigned h0, m0, l0, h1, m1, l1;
                split3(v0, h0, m0, l0);
                split3(v1, h1, m1, l1);
                pk0[jj] = h0 | (h1 << 16);
                pk1[jj] = m0 | (m1 << 16);
                pk2[jj] = l0 | (l1 << 16);
                x2part = fmaf(v0, v0, x2part);
                x2part = fmaf(v1, v1, x2part);
            }
            int base = px * ROWU + h * 16 + g * 8;    // ushort idx; byte 16-aligned
            *(uint4*)&Ap[0][base] = make_uint4(pk0[0], pk0[1], pk0[2], pk0[3]);
            *(uint4*)&Ap[1][base] = make_uint4(pk1[0], pk1[1], pk1[2], pk1[3]);
            *(uint4*)&Ap[2][base] = make_uint4(pk2[0], pk2[1], pk2[2], pk2[3]);
        }
        if (ci == 7) x2p[h][px] = x2part;

        // ---- prefetch next x chunk into xr (consumed next convert phase) ----
        if (ci < 7) {
#pragma unroll
            for (int j = 0; j < 16; ++j)
                xr[j] = xg[(size_t)((ci + 1) * 32 + h * 16 + j) * PIX];
        }

        __syncthreads();   // bar1: Ap ready

        // ---- MFMA phase: A-frag ds_read_b128 once per (plane, m);
        // pairs: pa=0 -> pb{0,1,2}; pa=1 -> pb{0,1}; pa=2 -> pb{0}.
#pragma unroll
        for (int pa = 0; pa < 3; ++pa) {
            const int npb = (pa == 0) ? 3 : ((pa == 1) ? 2 : 1);
#pragma unroll
            for (int m = 0; m < 8; ++m) {
                short8 af = *(const short8*)&Ap[pa][(m * 16 + l15) * ROWU + q * 8];
#pragma unroll
                for (int pb2 = 0; pb2 < 3; ++pb2) {
                    if (pb2 < npb) {
                        acc[m][0] = __builtin_amdgcn_mfma_f32_16x16x32_bf16(af, bv[pb2][0], acc[m][0], 0, 0, 0);
                        acc[m][1] = __builtin_amdgcn_mfma_f32_16x16x32_bf16(af, bv[pb2][1], acc[m][1], 0, 0, 0);
                    }
                }
            }
        }
        __syncthreads();   // bar2: all Ap reads done before next convert writes
    }

    // ---- epilogue: dist = (x2 - 2*S) + c2, argmin over n (proven exact) ----
    const float c2a0 = c2v[w * 32 + l15];
    const float c2a1 = c2v[w * 32 + 16 + l15];
    const unsigned n0 = (unsigned)(w * 32 + l15);
    const unsigned n1 = n0 + 16;

#pragma unroll
    for (int m = 0; m < 8; ++m) {
#pragma unroll
        for (int r = 0; r < 4; ++r) {
            int pxl = m * 16 + q * 4 + r;             // C/D: row = quad*4 + reg
            float x2v = x2p[0][pxl] + x2p[1][pxl];
            float d0 = (x2v - 2.0f * acc[m][0][r]) + c2a0;
            float d1 = (x2v - 2.0f * acc[m][1][r]) + c2a1;
            unsigned long long k0 = ((unsigned long long)mono(d0) << 32) | n0;
            unsigned long long k1 = ((unsigned long long)mono(d1) << 32) | n1;
            unsigned long long best = umin64(k0, k1);
            best = umin64(best, __shfl_xor(best, 1));
            best = umin64(best, __shfl_xor(best, 2));
            best = umin64(best, __shfl_xor(best, 4));
            best = umin64(best, __shfl_xor(best, 8));
            if (l15 == 0) red[w][pxl] = best;
        }
    }
    __syncthreads();

    if (t < 128) {
        unsigned long long m0 = umin64(umin64(red[0][t], red[1][t]),
                                       umin64(red[2][t], red[3][t]));
        code[(size_t)img * PIX + pb + t] = (unsigned char)(m0 & 0xFFu);
    }
}

// K2: 4 histogram tiles per 256-thread block (proven-exact kernel)
__global__ __launch_bounds__(256) void hist_kernel(const unsigned char* __restrict__ code,
                                                   float* __restrict__ out) {
    __shared__ int hist[4][K_DIM + 1];
    int wid = threadIdx.x >> 6, lane = threadIdx.x & 63;
    int b = blockIdx.x * 4 + wid;
    int n = b >> 6, sy = (b >> 3) & 7, sx = b & 7;

    hist[wid][lane] = 0;
    hist[wid][lane + 64] = 0;
    if (lane == 0) hist[wid][128] = 0;
    __syncthreads();

    int hh = sy * 8 + (lane >> 3);
    int ww = sx * 8 + (lane & 7);
    int c = code[n * PIX + hh * HW_DIM + ww];
    atomicAdd(&hist[wid][c + 1], 1);
    __syncthreads();

    const float inv = 1.0f / 64.0f;
    out[(size_t)b * (K_DIM + 1) + lane] = hist[wid][lane] * inv;
    out[(size_t)b * (K_DIM + 1) + 64 + lane] = hist[wid][lane + 64] * inv;
    if (lane == 0) out[(size_t)b * (K_DIM + 1) + 128] = hist[wid][128] * inv;
}

extern "C" void kernel_launch(void* const* d_in, const int* in_sizes, int n_in,
                              void* d_out, int out_size, void* d_ws, size_t ws_size,
                              hipStream_t stream) {
    const float* x  = (const float*)d_in[0];       // (32, 256, 64, 64) fp32
    const float* cl = (const float*)d_in[1];       // (128, 256) fp32
    float* out = (float*)d_out;                    // (32, 64, 129) fp32

    unsigned short* Bt = (unsigned short*)d_ws;                  // 196608 B
    float* c2 = (float*)((char*)d_ws + 196608);                  // 512 B
    unsigned char* code = (unsigned char*)d_ws + 197120;         // 131072 B

    prep_kernel<<<K_DIM, 64, 0, stream>>>(cl, Bt, c2);
    main_kernel<<<(N_IMG * PIX) / 128, 256, 0, stream>>>(x, Bt, c2, code);
    hist_kernel<<<(N_IMG * 64) / 4, 256, 0, stream>>>(code, out);
}

// Round 7
// 226.325 us; speedup vs baseline: 3.2981x; 1.0081x over previous
//
#include <hip/hip_runtime.h>

#define C_DIM 256
#define K_DIM 128
#define HW_DIM 64
#define PIX 4096
#define N_IMG 32

using short8 = __attribute__((ext_vector_type(8))) short;
using f32x4  = __attribute__((ext_vector_type(4))) float;

// CK-style barrier: waits own LDS ops (lgkmcnt) only — leaves global-load
// prefetches (vmcnt) in flight across the barrier, unlike __syncthreads().
__device__ __forceinline__ void lds_barrier() {
    asm volatile("s_waitcnt lgkmcnt(0)\n\ts_barrier" ::: "memory");
}

__device__ __forceinline__ unsigned long long umin64(unsigned long long a, unsigned long long b) {
    return a < b ? a : b;
}
__device__ __forceinline__ unsigned mono(float d) {
    unsigned u = __float_as_uint(d);
    return u ^ ((u & 0x80000000u) ? 0xFFFFFFFFu : 0x80000000u);
}

// Truncation split: v = hi + mid + lo, each term = top-16-bit bitmask value
// (exact Sterbenz residuals; lo ~ 2^-16 * v). Cheap: and/sub only.
__device__ __forceinline__ void split3t(float v, unsigned& hu, unsigned& mu, unsigned& lu) {
    unsigned u = __float_as_uint(v);
    unsigned hf = u & 0xffff0000u;
    float r1 = v - __uint_as_float(hf);
    unsigned r1u = __float_as_uint(r1);
    unsigned mf = r1u & 0xffff0000u;
    float r2 = r1 - __uint_as_float(mf);
    hu = u; mu = r1u; lu = __float_as_uint(r2);   // consumers take >>16
}

// P: per cluster k: trunc 3-way split -> Bt[k][768] (planes hi/mid/lo) + exact c2
__global__ __launch_bounds__(64) void prep_kernel(const float* __restrict__ cl,
                                                  unsigned short* __restrict__ Bt,
                                                  float* __restrict__ c2) {
    int k = blockIdx.x;
    int lane = threadIdx.x;
    const float4* row = (const float4*)(cl + k * C_DIM);
    float4 v = row[lane];
    float vv[4] = {v.x, v.y, v.z, v.w};
    unsigned short* bk = Bt + k * 768 + lane * 4;
#pragma unroll
    for (int i = 0; i < 4; ++i) {
        unsigned hu, mu, lu;
        split3t(vv[i], hu, mu, lu);
        bk[i]       = (unsigned short)(hu >> 16);
        bk[256 + i] = (unsigned short)(mu >> 16);
        bk[512 + i] = (unsigned short)(lu >> 16);
    }
    if (lane == 0) {   // identical op order to proven-exact c2
        float s = 0.f;
#pragma unroll
        for (int i = 0; i < C_DIM / 4; ++i) {
            float4 u = row[i];
            s = fmaf(u.x, u.x, s);
            s = fmaf(u.y, u.y, s);
            s = fmaf(u.z, u.z, s);
            s = fmaf(u.w, u.w, s);
        }
        c2[k] = s;
    }
}

// Main: block = 256 thr (4 waves), S[128px][128k] via 16x16x32 bf16 MFMA,
// 6 cross-term pairs (h,h)(h,m)(h,l)(m,h)(m,m)(l,h); per-acc term order
// identical to proven rounds 5/6. A staged in LDS in FRAGMENT ORDER:
// plane p, tile m, lane L hold ushorts at p*4096 + m*512 + L*8 -> reads are
// lane-contiguous ds_read_b128 (0 conflicts); writes 2-way (free).
__global__ __launch_bounds__(256) void main_kernel(
    const float* __restrict__ x, const unsigned short* __restrict__ Bt,
    const float* __restrict__ c2v, unsigned char* __restrict__ code) {

    __shared__ __align__(16) unsigned short Ap[3 * 4096];   // 24576 B
    __shared__ float x2p[2][128];                           // 1024 B
    unsigned long long* red = (unsigned long long*)Ap;      // aliased (epilogue only)

    const int t    = threadIdx.x;
    const int lane = t & 63;
    const int w    = t >> 6;
    const int q    = lane >> 4;
    const int l15  = lane & 15;

    const int px = t & 127;        // conversion: this thread's pixel row
    const int h  = t >> 7;         // conversion: c-half (0: c 0-15, 1: c 16-31)

    const int b   = blockIdx.x;
    const int img = b >> 5;
    const int pb  = (b & 31) * 128;

    const float* xg = x + (size_t)img * (C_DIM * PIX) + pb + px;

    f32x4 acc[8][2];
#pragma unroll
    for (int m = 0; m < 8; ++m)
#pragma unroll
        for (int ns = 0; ns < 2; ++ns) acc[m][ns] = (f32x4){0.f, 0.f, 0.f, 0.f};

    float xr[16];
#pragma unroll
    for (int j = 0; j < 16; ++j) xr[j] = xg[(size_t)(h * 16 + j) * PIX];

    float x2part = 0.f;
    const unsigned short* btb = Bt + (w * 32 + l15) * 768 + q * 8;

    // convert-phase LDS write base (ushort idx within a plane)
    const int wbase = (px >> 4) * 512 + (px & 15) * 8 + h * 2 * 128;

#pragma unroll 1
    for (int ci = 0; ci < 8; ++ci) {
        // ---- B-fragments: 6 unique (plane x n-half), L2-hot; consumed in the
        // MFMA phase ~300+ cyc later (latency hidden; survives lds_barrier).
        short8 bv[3][2];
#pragma unroll
        for (int p = 0; p < 3; ++p) {
            bv[p][0] = *(const short8*)(btb + p * 256 + ci * 32);
            bv[p][1] = *(const short8*)(btb + 16 * 768 + p * 256 + ci * 32);
        }

        // ---- convert xr -> 3 bf16 planes in LDS (trunc split) + x2 ----
#pragma unroll
        for (int g = 0; g < 2; ++g) {
            unsigned p0[4], p1[4], p2[4];
#pragma unroll
            for (int jj = 0; jj < 4; ++jj) {
                float v0 = xr[g * 8 + jj * 2], v1 = xr[g * 8 + jj * 2 + 1];
                unsigned h0, m0, l0, h1, m1, l1;
                split3t(v0, h0, m0, l0);
                split3t(v1, h1, m1, l1);
                p0[jj] = (h0 >> 16) | (h1 & 0xffff0000u);
                p1[jj] = (m0 >> 16) | (m1 & 0xffff0000u);
                p2[jj] = (l0 >> 16) | (l1 & 0xffff0000u);
                x2part = fmaf(v0, v0, x2part);
                x2part = fmaf(v1, v1, x2part);
            }
            int base = wbase + g * 128;   // (q = h*2+g) * 16 lanes * 8 ushorts
            *(uint4*)&Ap[base]            = make_uint4(p0[0], p0[1], p0[2], p0[3]);
            *(uint4*)&Ap[4096 + base]     = make_uint4(p1[0], p1[1], p1[2], p1[3]);
            *(uint4*)&Ap[8192 + base]     = make_uint4(p2[0], p2[1], p2[2], p2[3]);
        }
        if (ci == 7) x2p[h][px] = x2part;

        // ---- prefetch next x chunk (vmcnt survives the barriers below) ----
        if (ci < 7) {
#pragma unroll
            for (int j = 0; j < 16; ++j)
                xr[j] = xg[(size_t)((ci + 1) * 32 + h * 16 + j) * PIX];
        }

        lds_barrier();   // Ap ready (LDS-only wait)

        // ---- MFMA: pa outer, m-pairs, pb inner; per-acc term order =
        // pa ascending then pb ascending (identical to rounds 5/6).
#pragma unroll
        for (int pa = 0; pa < 3; ++pa) {
#pragma unroll
            for (int mg = 0; mg < 4; ++mg) {
                const int m0 = mg * 2, m1 = mg * 2 + 1;
                short8 af0 = *(const short8*)&Ap[pa * 4096 + m0 * 512 + lane * 8];
                short8 af1 = *(const short8*)&Ap[pa * 4096 + m1 * 512 + lane * 8];
#pragma unroll
                for (int pb2 = 0; pb2 < 3; ++pb2) {
                    if (pb2 < 3 - pa) {
                        acc[m0][0] = __builtin_amdgcn_mfma_f32_16x16x32_bf16(af0, bv[pb2][0], acc[m0][0], 0, 0, 0);
                        acc[m0][1] = __builtin_amdgcn_mfma_f32_16x16x32_bf16(af0, bv[pb2][1], acc[m0][1], 0, 0, 0);
                        acc[m1][0] = __builtin_amdgcn_mfma_f32_16x16x32_bf16(af1, bv[pb2][0], acc[m1][0], 0, 0, 0);
                        acc[m1][1] = __builtin_amdgcn_mfma_f32_16x16x32_bf16(af1, bv[pb2][1], acc[m1][1], 0, 0, 0);
                    }
                }
            }
        }
        lds_barrier();   // all Ap reads done before next convert overwrites
    }

    // ---- epilogue: dist = (x2 - 2*S) + c2, argmin (proven exact) ----
    const float c2a0 = c2v[w * 32 + l15];
    const float c2a1 = c2v[w * 32 + 16 + l15];
    const unsigned n0 = (unsigned)(w * 32 + l15);
    const unsigned n1 = n0 + 16;

#pragma unroll
    for (int m = 0; m < 8; ++m) {
#pragma unroll
        for (int r = 0; r < 4; ++r) {
            int pxl = m * 16 + q * 4 + r;             // C/D: row = quad*4 + reg
            float x2v = x2p[0][pxl] + x2p[1][pxl];
            float d0 = (x2v - 2.0f * acc[m][0][r]) + c2a0;
            float d1 = (x2v - 2.0f * acc[m][1][r]) + c2a1;
            unsigned long long k0 = ((unsigned long long)mono(d0) << 32) | n0;
            unsigned long long k1 = ((unsigned long long)mono(d1) << 32) | n1;
            unsigned long long best = umin64(k0, k1);
            best = umin64(best, __shfl_xor(best, 1));
            best = umin64(best, __shfl_xor(best, 2));
            best = umin64(best, __shfl_xor(best, 4));
            best = umin64(best, __shfl_xor(best, 8));
            if (l15 == 0) red[w * 128 + pxl] = best;
        }
    }
    lds_barrier();

    if (t < 128) {
        unsigned long long m0 = umin64(umin64(red[t], red[128 + t]),
                                       umin64(red[256 + t], red[384 + t]));
        code[(size_t)img * PIX + pb + t] = (unsigned char)(m0 & 0xFFu);
    }
}

// K2: 4 histogram tiles per 256-thread block (proven-exact kernel)
__global__ __launch_bounds__(256) void hist_kernel(const unsigned char* __restrict__ code,
                                                   float* __restrict__ out) {
    __shared__ int hist[4][K_DIM + 1];
    int wid = threadIdx.x >> 6, lane = threadIdx.x & 63;
    int b = blockIdx.x * 4 + wid;
    int n = b >> 6, sy = (b >> 3) & 7, sx = b & 7;

    hist[wid][lane] = 0;
    hist[wid][lane + 64] = 0;
    if (lane == 0) hist[wid][128] = 0;
    __syncthreads();

    int hh = sy * 8 + (lane >> 3);
    int ww = sx * 8 + (lane & 7);
    int c = code[n * PIX + hh * HW_DIM + ww];
    atomicAdd(&hist[wid][c + 1], 1);
    __syncthreads();

    const float inv = 1.0f / 64.0f;
    out[(size_t)b * (K_DIM + 1) + lane] = hist[wid][lane] * inv;
    out[(size_t)b * (K_DIM + 1) + 64 + lane] = hist[wid][lane + 64] * inv;
    if (lane == 0) out[(size_t)b * (K_DIM + 1) + 128] = hist[wid][128] * inv;
}

extern "C" void kernel_launch(void* const* d_in, const int* in_sizes, int n_in,
                              void* d_out, int out_size, void* d_ws, size_t ws_size,
                              hipStream_t stream) {
    const float* x  = (const float*)d_in[0];       // (32, 256, 64, 64) fp32
    const float* cl = (const float*)d_in[1];       // (128, 256) fp32
    float* out = (float*)d_out;                    // (32, 64, 129) fp32

    unsigned short* Bt = (unsigned short*)d_ws;                  // 196608 B
    float* c2 = (float*)((char*)d_ws + 196608);                  // 512 B
    unsigned char* code = (unsigned char*)d_ws + 197120;         // 131072 B

    prep_kernel<<<K_DIM, 64, 0, stream>>>(cl, Bt, c2);
    main_kernel<<<(N_IMG * PIX) / 128, 256, 0, stream>>>(x, Bt, c2, code);
    hist_kernel<<<(N_IMG * 64) / 4, 256, 0, stream>>>(code, out);
}